// Round 13
// baseline (207.058 us; speedup 1.0000x reference)
//
#include <hip/hip_runtime.h>

// Attention block: x[2,2048,1024] fp32, w_qkv[3072,1024], w_out[1024,1024], b_out[1024]
// bf16 MFMA GEMMs + flash attention.
// Round 23: r22's GEMM dbuf regressed (+6.8us; counted-vmcnt now 0-for-3 on
// this problem — TLP already covers staging latency). GEMMs reverted to r21
// (187.1us verified). NEW: combine_kernel deleted — gemm_out's A-staging
// computes A = cvt_pk((pO0+pO1)*inv) in-register (reg-stage: 2x uint4 loads
// at the same pre-swizzled source column, VALU combine, ds_write_b128 to the
// same linear LDS slot; B stays gld16 DMA; plain __syncthreads handles all
// waits). RNE cvt_pk == combine's f2bf -> bit-identical A, absmax unchanged.
// Saves one dispatch + 16.8MB of ob traffic.

typedef __attribute__((ext_vector_type(4))) float f32x4;
typedef __attribute__((ext_vector_type(8))) __bf16 bf16x8;
typedef unsigned short u16;

#define DEV static __device__ __forceinline__

DEV u16 f2bf(float x) {  // RNE float->bf16 (epilogues only)
  union { float f; unsigned u; } c; c.f = x;
  unsigned r = c.u + 0x7FFFu + ((c.u >> 16) & 1u);
  return (u16)(r >> 16);
}

DEV float bf2f(unsigned lo16) {  // bf16 (in low 16 bits) -> float
  union { unsigned u; float f; } c; c.u = lo16 << 16; return c.f;
}

DEV void gld16(const void* g, void* l) {  // async global->LDS, 16B/lane
  __builtin_amdgcn_global_load_lds((__attribute__((address_space(1))) void*)g,
                                   (__attribute__((address_space(3))) void*)l, 16, 0, 0);
}

// Fused fp32->bf16 convert for all three tensors (one dispatch).
__global__ __launch_bounds__(256) void cvt_all_kernel(const float* __restrict__ x,
                                                      const float* __restrict__ wq,
                                                      const float* __restrict__ wo,
                                                      u16* __restrict__ xo,
                                                      u16* __restrict__ wqo,
                                                      u16* __restrict__ woo) {
  int t = blockIdx.x * 256 + threadIdx.x;
  const float* in; u16* out; int i;
  if (t < 1048576)       { in = x;  out = xo;  i = t; }
  else if (t < 1835008)  { in = wq; out = wqo; i = t - 1048576; }
  else                   { in = wo; out = woo; i = t - 1835008; }
  float4 v = ((const float4*)in)[i];
  uint2 o;
  o.x = (unsigned)f2bf(v.x) | ((unsigned)f2bf(v.y) << 16);
  o.y = (unsigned)f2bf(v.z) | ((unsigned)f2bf(v.w) << 16);
  ((uint2*)out)[i] = o;
}

// C = A[M,K] * B[N,K]^T, 128x128 tile, BK=32, 4 waves of 64x64, bf16 MFMA.
// Grid: flat 768 blocks, bijective XCD grouping. Source-side chunk-XOR
// swizzle (rule #21): thread tid loads global chunk (tid&3)^((r0>>1)&3)
// into linear LDS slot tid; reads use quad^((l15>>1)&3). Single-buffered
// (r21 verified; dbuf regressed in r22).
// Epilogue: scatter to q/k/v buffers [B=2,H=16,L=2048,Dh=64] bf16.
// Q is pre-scaled by scale*log2(e) so flash can exp2 the raw MFMA output.
__global__ __launch_bounds__(256) void gemm_qkv_kernel(const u16* __restrict__ A,
                                                       const u16* __restrict__ Bw,
                                                       u16* __restrict__ qb,
                                                       u16* __restrict__ kb,
                                                       u16* __restrict__ vb) {
  __shared__ alignas(16) u16 As[128 * 32];
  __shared__ alignas(16) u16 Bs[128 * 32];
  const int K = 1024;
  int f = blockIdx.x;
  int xcd = f & 7, idx = f >> 3;          // 8 XCDs x 96 blocks
  int nt = xcd * 3 + idx % 3;             // 0..23
  int mt = idx / 3;                       // 0..31
  int tid = threadIdx.x, wave = tid >> 6, lane = tid & 63, quad = lane >> 4, l15 = lane & 15;
  int m0 = mt * 128, n0 = nt * 128;
  f32x4 z = {0.f, 0.f, 0.f, 0.f};
  f32x4 acc[4][4];
  for (int i = 0; i < 4; i++) for (int j = 0; j < 4; j++) acc[i][j] = z;
  int r0 = tid >> 2;
  int kos = ((tid & 3) ^ ((r0 >> 1) & 3)) * 8;  // pre-swizzled global chunk
  const u16* ga0 = A + (m0 + r0) * K + kos;
  const u16* ga1 = A + (m0 + r0 + 64) * K + kos;   // ((r0+64)>>1)&3 == (r0>>1)&3
  const u16* gb0 = Bw + (n0 + r0) * K + kos;
  const u16* gb1 = Bw + (n0 + r0 + 64) * K + kos;
  u16 *la0 = &As[tid * 8], *la1 = &As[(256 + tid) * 8];   // linear dests
  u16 *lb0 = &Bs[tid * 8], *lb1 = &Bs[(256 + tid) * 8];
  int ar = (wave & 1) * 64, bc = (wave >> 1) * 64;
  int cA = (quad ^ ((l15 >> 1) & 3)) * 8;  // swizzled read chunk
  for (int k0 = 0; k0 < K; k0 += 32) {
    gld16(ga0 + k0, la0); gld16(ga1 + k0, la1);
    gld16(gb0 + k0, lb0); gld16(gb1 + k0, lb1);
    __syncthreads();
    bf16x8 af[4], bfr[4];
    for (int i = 0; i < 4; i++) af[i]  = *(const bf16x8*)&As[(ar + i * 16 + l15) * 32 + cA];
    for (int j = 0; j < 4; j++) bfr[j] = *(const bf16x8*)&Bs[(bc + j * 16 + l15) * 32 + cA];
    for (int i = 0; i < 4; i++)
      for (int j = 0; j < 4; j++)
        acc[i][j] = __builtin_amdgcn_mfma_f32_16x16x32_bf16(af[i], bfr[j], acc[i][j], 0, 0, 0);
    __syncthreads();
  }
  int which = n0 >> 10;  // block-uniform: 0=q 1=k 2=v
  u16* dst = which == 0 ? qb : (which == 1 ? kb : vb);
  float qs = which == 0 ? 0.045112882054311f : 1.0f;  // (1/32)*log2(e)
  for (int i = 0; i < 4; i++)
    for (int j = 0; j < 4; j++) {
      int o = n0 + bc + j * 16 + l15;
      int h = (o & 1023) >> 6, d = o & 63;
      for (int r = 0; r < 4; r++) {
        int m = m0 + ar + i * 16 + quad * 4 + r;
        int b = m >> 11, l = m & 2047;
        dst[((b * 16 + h) * 2048 + l) * 64 + d] = f2bf(acc[i][j][r] * qs);
      }
    }
}

// v[bh][l][d] -> vt[bh][d][l'], where within each 32-key tile the stored key
// order is the kappa slot order: stored position p holds key
// k = ((p>>3)&3)*4 + (p&3) + 16*((p>>2)&1)   (p = quad*8 + w).
// This makes flash's PV B-fragment a single b128 per d-block.
__global__ __launch_bounds__(256) void transpose_v_kernel(const u16* __restrict__ vb,
                                                          u16* __restrict__ vtb) {
  __shared__ alignas(16) u16 T[64 * 72];
  int lt = blockIdx.x, bh = blockIdx.y;
  int t = threadIdx.x;
  for (int ld = 0; ld < 2; ld++) {
    int idx = ld * 256 + t;
    int l = idx >> 3, d0 = (idx & 7) * 8;
    uint4 v = *(const uint4*)(vb + (bh * 2048 + lt * 64 + l) * 64 + d0);
    *(uint4*)&T[l * 72 + d0] = v;
  }
  __syncthreads();
  for (int ld = 0; ld < 2; ld++) {
    int idx = ld * 256 + t;
    int d = idx >> 3, p0 = (idx & 7) * 8;
    int sub = p0 >> 5, quad = (p0 >> 3) & 3;
    union { u16 us[8]; uint4 v; } tmp;
    for (int w2 = 0; w2 < 8; w2++) {
      int k = sub * 32 + quad * 4 + (w2 & 3) + 16 * (w2 >> 2);
      tmp.us[w2] = T[k * 72 + d];
    }
    *(uint4*)(vtb + (bh * 64 + d) * 2048 + lt * 64 + p0) = tmp.v;
  }
}

// Flash attention v10 (r13 verified, 44.9us): 128 threads = 2 waves x 32
// q-rows, 64-row q-tile, 32-key tiles x 32 iterations, keys split in half.
// Grid: flat 2048 blocks, bijective XCD remap (each XCD owns 4 bh; K/V
// L2-resident, FETCH 12.3MB verified). K/V: LDS dbuf DMA, XOR-swizzled.
// Swapped QK: s = mfma(K,Q) = S^T, lane l15 = q; exp2 + v_cvt_pk_bf16_f32
// pack in register forms the PV A-fragment under kappa; V pre-permuted to
// kappa order so the B-fragment is one conflict-free b128 per d-block.
// Denominator from unrounded exp values. LDS 16384 B.
__global__ __launch_bounds__(128, 4) void flash_kernel(const u16* __restrict__ qb,
                                                       const u16* __restrict__ kb,
                                                       const u16* __restrict__ vtb,
                                                       u16* __restrict__ pO0,
                                                       u16* __restrict__ pO1,
                                                       float* __restrict__ dn) {
  __shared__ alignas(16) u16 Ks[2][32 * 64];
  __shared__ alignas(16) u16 Vts[2][64 * 32];
  int f = blockIdx.x;
  int w = (f & 7) * 256 + (f >> 3);  // bijective XCD grouping (T1)
  int bh = w >> 6, ph = (w >> 5) & 1, qt = w & 31;
  int b = bh >> 4, h = bh & 15;
  int tid = threadIdx.x, wave = tid >> 6, lane = tid & 63, quad = lane >> 4, l15 = lane & 15;
  int q0 = qt * 64;
  int kbase = ph * 1024;  // this block's key range: kbase .. kbase+1023
  u16* pO = ph ? pO1 : pO0;
  const u16* qg = qb + (bh * 2048 + q0) * 64;
  const u16* kgb = kb + (bh * 2048 + kbase) * 64;
  const u16* vgb = vtb + bh * 64 * 2048 + kbase;

  // Q fragments: direct global->VGPR, once (16B contiguous rows of qb;
  // vmcnt retires before the kt loop — not barrier-drained per iteration)
  bf16x8 aq[2][2];
  for (int i = 0; i < 2; i++)
    for (int kk = 0; kk < 2; kk++)
      aq[i][kk] = *(const bf16x8*)(qg + (wave * 32 + i * 16 + l15) * 64 + kk * 32 + quad * 8);

  // stage K/V tile 0 into buffer 0 (4 KB each; 128 thr x 2 iters x 16 B)
  for (int it = 0; it < 2; it++) {
    int idx = it * 128 + tid;
    int kr = idx >> 3, kblk = (idx & 7) ^ (kr & 7);
    gld16(kgb + kr * 64 + kblk * 8, &Ks[0][idx * 8]);
    int vr = idx >> 2, vblk = (idx & 3) ^ ((vr >> 1) & 3);
    gld16(vgb + vr * 2048 + vblk * 8, &Vts[0][idx * 8]);
  }
  __syncthreads();

  f32x4 z = {0.f, 0.f, 0.f, 0.f};
  f32x4 o_[2][4];
  for (int i = 0; i < 2; i++) for (int j = 0; j < 4; j++) o_[i][j] = z;
  float dnacc[2] = {0.f, 0.f};

  // K fragment addresses (XOR swizzle, verified r8): row l15, logical k-chunk
  // quad (kbA) / quad+4 (kbB); physical = logical ^ (l15&7).
  int kro = l15 * 64;
  int kbA = 8 * ((quad) ^ (l15 & 7));
  int kbB = 8 * ((4 + quad) ^ (l15 & 7));
  // V b128 read offset (kappa-ordered vtb): row l15 (stride 32 u16), logical
  // 8-slot block quad, physical = quad ^ ((l15>>1)&3)  (r11 pattern, 0 conf).
  int vro = l15 * 32 + 8 * (quad ^ ((l15 >> 1) & 3));

#pragma unroll 2
  for (int kt = 0; kt < 32; kt++) {
    int cur = kt & 1;
    if (kt < 31) {  // DMA-prefetch next K/V tile into alternate buffer
      int nxt = cur ^ 1;
      for (int it = 0; it < 2; it++) {
        int idx = it * 128 + tid;
        int kr = idx >> 3, kblk = (idx & 7) ^ (kr & 7);
        gld16(kgb + ((kt + 1) * 32 + kr) * 64 + kblk * 8, &Ks[nxt][idx * 8]);
        int vr = idx >> 2, vblk = (idx & 3) ^ ((vr >> 1) & 3);
        gld16(vgb + vr * 2048 + (kt + 1) * 32 + vblk * 8, &Vts[nxt][idx * 8]);
      }
    }
    const u16* ks = Ks[cur];
    const u16* vs = Vts[cur];
    // K fragments: 4 b128 (j = key block 0/1, kk = k half)
    bf16x8 bk[2][2];
    for (int j = 0; j < 2; j++) {
      bk[j][0] = *(const bf16x8*)&ks[j * 1024 + kro + kbA];
      bk[j][1] = *(const bf16x8*)&ks[j * 1024 + kro + kbB];
    }
    // Swapped QK: S^T[key][q] (lane: col=l15=q, row=quad*4+r=key), K=64
    f32x4 s[2][2];
    __builtin_amdgcn_s_setprio(1);
    for (int i = 0; i < 2; i++)
      for (int j = 0; j < 2; j++) {
        s[i][j] = __builtin_amdgcn_mfma_f32_16x16x32_bf16(bk[j][0], aq[i][0], z, 0, 0, 0);
        s[i][j] = __builtin_amdgcn_mfma_f32_16x16x32_bf16(bk[j][1], aq[i][1], s[i][j], 0, 0, 0);
      }
    __builtin_amdgcn_s_setprio(0);
    // exp2 (Q pre-scaled) -> PV A-fragment via v_cvt_pk_bf16_f32 (RNE; slot w
    // holds key kappa(quad,w)). Denominator accumulates unrounded exp values.
    bf16x8 ap[2];
    for (int i = 0; i < 2; i++) {
      unsigned w4[4];
      for (int j = 0; j < 2; j++)
        for (int rp = 0; rp < 2; rp++) {
          float pa = __builtin_amdgcn_exp2f(s[i][j][2 * rp]);
          float pb = __builtin_amdgcn_exp2f(s[i][j][2 * rp + 1]);
          asm("v_cvt_pk_bf16_f32 %0, %1, %2" : "=v"(w4[j * 2 + rp]) : "v"(pa), "v"(pb));
          dnacc[i] += pa + pb;
        }
      union { uint4 u; bf16x8 v; } apu;
      apu.u.x = w4[0]; apu.u.y = w4[1]; apu.u.z = w4[2]; apu.u.w = w4[3];
      ap[i] = apu.v;
    }
    // V fragments: 4 b128 (j = d block), kappa slot order, conflict-free
    bf16x8 bv[4];
    for (int j = 0; j < 4; j++) bv[j] = *(const bf16x8*)&vs[j * 512 + vro];
    // PV: O[q][d] += P kappa-slots x V kappa-slots (K=32, 1 MFMA per (i,j))
    __builtin_amdgcn_s_setprio(1);
    for (int i = 0; i < 2; i++)
      for (int j = 0; j < 4; j++)
        o_[i][j] = __builtin_amdgcn_mfma_f32_16x16x32_bf16(ap[i], bv[j], o_[i][j], 0, 0, 0);
    __builtin_amdgcn_s_setprio(0);
    __syncthreads();  // drains next-tile DMA (only DMA is in flight); fences reuse
  }
  // denominator: lane (l15=q) holds partial sum over its quad's keys;
  // reduce across quads (lanes l15+16*quad), then quad 0 writes.
  for (int i = 0; i < 2; i++) {
    dnacc[i] += __shfl_xor(dnacc[i], 16, 64);
    dnacc[i] += __shfl_xor(dnacc[i], 32, 64);
  }
  // partial numerator (bf16) + partial denominator (fp32)
  for (int i = 0; i < 2; i++) {
    for (int j = 0; j < 4; j++) {
      int c = h * 64 + j * 16 + l15;
      for (int r = 0; r < 4; r++) {
        int q = q0 + wave * 32 + i * 16 + quad * 4 + r;
        pO[(b * 2048 + q) * 1024 + c] = f2bf(o_[i][j][r]);
      }
    }
    if (quad == 0) {
      int q = q0 + wave * 32 + i * 16 + l15;
      dn[ph * 65536 + bh * 2048 + q] = dnacc[i];
    }
  }
}

// out[M,N] = combine(pO0,pO1,dn)[M,K] * B[N,K]^T + bias[N], fp32 out.
// 128x64 tile, flat 512 blocks, bijective XCD grouping. A is produced
// IN-STAGE: A[m][c] = cvt_pk((pO0+pO1) * 1/(dn0+dn1)) — reg-stage with the
// same pre-swizzled source column kos, ds_write_b128 to the same linear LDS
// slot (read side unchanged). Bit-identical to the old combine+DMA path.
__global__ __launch_bounds__(256) void gemm_out_kernel(const u16* __restrict__ pO0,
                                                       const u16* __restrict__ pO1,
                                                       const float* __restrict__ dnb,
                                                       const u16* __restrict__ Bw,
                                                       const float* __restrict__ bias,
                                                       float* __restrict__ out) {
  __shared__ alignas(16) u16 As[128 * 32];
  __shared__ alignas(16) u16 Bs[64 * 32];
  const int K = 1024;
  int f = blockIdx.x;
  int xcd = f & 7, idx = f >> 3;          // 8 XCDs x 64 blocks
  int nt = xcd * 2 + (idx & 1);           // 0..15
  int mt = idx >> 1;                      // 0..31
  int tid = threadIdx.x, wave = tid >> 6, lane = tid & 63, quad = lane >> 4, l15 = lane & 15;
  int m0 = mt * 128, n0 = nt * 64;
  f32x4 z = {0.f, 0.f, 0.f, 0.f};
  f32x4 acc[4][2];
  for (int i = 0; i < 4; i++) for (int j = 0; j < 2; j++) acc[i][j] = z;
  int r0 = tid >> 2;
  int kos = ((tid & 3) ^ ((r0 >> 1) & 3)) * 8;  // pre-swizzled global chunk
  int mA0 = m0 + r0, mA1 = m0 + r0 + 64;
  const u16* p0a = pO0 + mA0 * 1024 + kos;
  const u16* p1a = pO1 + mA0 * 1024 + kos;
  const u16* p0b = pO0 + mA1 * 1024 + kos;
  const u16* p1b = pO1 + mA1 * 1024 + kos;
  // dn row bases: li(m,h) = ((m>>11)*16 + h)*2048 + (m&2047)
  const float* dna = dnb + (mA0 >> 11) * 32768 + (mA0 & 2047);
  const float* dnc = dnb + (mA1 >> 11) * 32768 + (mA1 & 2047);
  const u16* gb0 = Bw + (n0 + r0) * K + kos;
  u16 *la0 = &As[tid * 8], *la1 = &As[(256 + tid) * 8];   // linear dests
  u16 *lb0 = &Bs[tid * 8];
  int ar = (wave & 1) * 64, bc = (wave >> 1) * 32;
  int cA = (quad ^ ((l15 >> 1) & 3)) * 8;  // swizzled read chunk
  for (int k0 = 0; k0 < K; k0 += 32) {
    // B: async DMA (as before)
    gld16(gb0 + k0, lb0);
    // A: reg-stage + combine. h = (k0+kos)>>6 constant over the 8 elems.
    int ho = ((k0 + kos) >> 6) * 2048;
    float inv0 = 1.0f / (dna[ho] + dna[65536 + ho]);
    float inv1 = 1.0f / (dnc[ho] + dnc[65536 + ho]);
    uint4 u0 = *(const uint4*)(p0a + k0);
    uint4 u1 = *(const uint4*)(p1a + k0);
    uint4 u2 = *(const uint4*)(p0b + k0);
    uint4 u3 = *(const uint4*)(p1b + k0);
    uint4 w0, w1;
    {
      const unsigned* a = (const unsigned*)&u0;
      const unsigned* bq = (const unsigned*)&u1;
      unsigned* wp = (unsigned*)&w0;
      for (int i = 0; i < 4; i++) {
        float lo = (bf2f(a[i] & 0xffff) + bf2f(bq[i] & 0xffff)) * inv0;
        float hi = (bf2f(a[i] >> 16)    + bf2f(bq[i] >> 16))    * inv0;
        asm("v_cvt_pk_bf16_f32 %0, %1, %2" : "=v"(wp[i]) : "v"(lo), "v"(hi));
      }
      const unsigned* c = (const unsigned*)&u2;
      const unsigned* d = (const unsigned*)&u3;
      unsigned* wq = (unsigned*)&w1;
      for (int i = 0; i < 4; i++) {
        float lo = (bf2f(c[i] & 0xffff) + bf2f(d[i] & 0xffff)) * inv1;
        float hi = (bf2f(c[i] >> 16)    + bf2f(d[i] >> 16))    * inv1;
        asm("v_cvt_pk_bf16_f32 %0, %1, %2" : "=v"(wq[i]) : "v"(lo), "v"(hi));
      }
    }
    *(uint4*)la0 = w0;
    *(uint4*)la1 = w1;
    __syncthreads();
    bf16x8 af[4], bfr[2];
    for (int i = 0; i < 4; i++) af[i]  = *(const bf16x8*)&As[(ar + i * 16 + l15) * 32 + cA];
    for (int j = 0; j < 2; j++) bfr[j] = *(const bf16x8*)&Bs[(bc + j * 16 + l15) * 32 + cA];
    for (int i = 0; i < 4; i++)
      for (int j = 0; j < 2; j++)
        acc[i][j] = __builtin_amdgcn_mfma_f32_16x16x32_bf16(af[i], bfr[j], acc[i][j], 0, 0, 0);
    __syncthreads();
  }
  for (int i = 0; i < 4; i++)
    for (int j = 0; j < 2; j++) {
      int o = n0 + bc + j * 16 + l15;
      float bo = bias[o];
      for (int r = 0; r < 4; r++) {
        int m = m0 + ar + i * 16 + quad * 4 + r;
        out[m * 1024 + o] = acc[i][j][r] + bo;
      }
    }
}

extern "C" void kernel_launch(void* const* d_in, const int* in_sizes, int n_in,
                              void* d_out, int out_size, void* d_ws, size_t ws_size,
                              hipStream_t stream) {
  const float* x     = (const float*)d_in[0];
  const float* w_qkv = (const float*)d_in[1];
  const float* w_out = (const float*)d_in[2];
  const float* b_out = (const float*)d_in[3];
  float* out = (float*)d_out;
  u16* ws = (u16*)d_ws;
  u16* x_bf    = ws;             // 4194304  (dead after gemm_qkv -> reused as pO0)
  u16* wqkv_bf = ws + 4194304;   // 3145728  (dead after gemm_qkv -> reused as dn)
  u16* wout_bf = ws + 7340032;   // 1048576  (live until gemm_out)
  u16* qb      = ws + 8388608;   // 4194304  [B,H,L,64] (pre-scaled)
  u16* kb      = ws + 12582912;  // 4194304  [B,H,L,64]
  u16* vb      = ws + 16777216;  // 4194304  (dead after transpose_v -> reused as pO1)
  u16* vtb     = ws + 20971520;  // 4194304  [B,H,64,L] (kappa key order)
  u16* pO0     = x_bf;           // partial numerator, key half 0 (bf16)
  u16* pO1     = vb;             // partial numerator, key half 1 (bf16)
  float* dnb   = (float*)wqkv_bf; // partial denominators [2][32][2048] fp32

  cvt_all_kernel<<<8192, 256, 0, stream>>>(x, w_qkv, w_out, x_bf, wqkv_bf, wout_bf);
  gemm_qkv_kernel<<<768, 256, 0, stream>>>(x_bf, wqkv_bf, qb, kb, vb);
  transpose_v_kernel<<<dim3(32, 32), 256, 0, stream>>>(vb, vtb);
  flash_kernel<<<2048, 128, 0, stream>>>(qb, kb, vtb, pO0, pO1, dnb);
  gemm_out_kernel<<<512, 256, 0, stream>>>(pO0, pO1, dnb, wout_bf, b_out, out);
}

// Round 14
// 203.551 us; speedup vs baseline: 1.0172x; 1.0172x over previous
//
#include <hip/hip_runtime.h>

// Attention block: x[2,2048,1024] fp32, w_qkv[3072,1024], w_out[1024,1024], b_out[1024]
// bf16 MFMA GEMMs + flash attention.
// Round 24: r23's combine-fusion was correct but gemm_out thrashed (FETCH
// 68.6MB): n-major XCD grouping gave each XCD ALL m-tiles -> per-XCD A
// working set = full 16.8MB pO >> 4MB L2, and the 16 n-panel re-reads all
// missed to HBM. Fix: M-MAJOR grouping — XCD x owns mt [4x,4x+4) x all 16
// nt. Per-XCD: A (pO rows) 2MB + B (wout) 2MB = 4MB, both L2-resident; A
// re-reads become L2 hits. Everything else byte-identical to r23
// (= r21 + combine fused into gemm_out's A-stage).

typedef __attribute__((ext_vector_type(4))) float f32x4;
typedef __attribute__((ext_vector_type(8))) __bf16 bf16x8;
typedef unsigned short u16;

#define DEV static __device__ __forceinline__

DEV u16 f2bf(float x) {  // RNE float->bf16 (epilogues only)
  union { float f; unsigned u; } c; c.f = x;
  unsigned r = c.u + 0x7FFFu + ((c.u >> 16) & 1u);
  return (u16)(r >> 16);
}

DEV float bf2f(unsigned lo16) {  // bf16 (in low 16 bits) -> float
  union { unsigned u; float f; } c; c.u = lo16 << 16; return c.f;
}

DEV void gld16(const void* g, void* l) {  // async global->LDS, 16B/lane
  __builtin_amdgcn_global_load_lds((__attribute__((address_space(1))) void*)g,
                                   (__attribute__((address_space(3))) void*)l, 16, 0, 0);
}

// Fused fp32->bf16 convert for all three tensors (one dispatch).
__global__ __launch_bounds__(256) void cvt_all_kernel(const float* __restrict__ x,
                                                      const float* __restrict__ wq,
                                                      const float* __restrict__ wo,
                                                      u16* __restrict__ xo,
                                                      u16* __restrict__ wqo,
                                                      u16* __restrict__ woo) {
  int t = blockIdx.x * 256 + threadIdx.x;
  const float* in; u16* out; int i;
  if (t < 1048576)       { in = x;  out = xo;  i = t; }
  else if (t < 1835008)  { in = wq; out = wqo; i = t - 1048576; }
  else                   { in = wo; out = woo; i = t - 1835008; }
  float4 v = ((const float4*)in)[i];
  uint2 o;
  o.x = (unsigned)f2bf(v.x) | ((unsigned)f2bf(v.y) << 16);
  o.y = (unsigned)f2bf(v.z) | ((unsigned)f2bf(v.w) << 16);
  ((uint2*)out)[i] = o;
}

// C = A[M,K] * B[N,K]^T, 128x128 tile, BK=32, 4 waves of 64x64, bf16 MFMA.
// Grid: flat 768 blocks, bijective XCD grouping. Source-side chunk-XOR
// swizzle (rule #21): thread tid loads global chunk (tid&3)^((r0>>1)&3)
// into linear LDS slot tid; reads use quad^((l15>>1)&3). Single-buffered
// (r21 verified; dbuf regressed in r22).
// Epilogue: scatter to q/k/v buffers [B=2,H=16,L=2048,Dh=64] bf16.
// Q is pre-scaled by scale*log2(e) so flash can exp2 the raw MFMA output.
__global__ __launch_bounds__(256) void gemm_qkv_kernel(const u16* __restrict__ A,
                                                       const u16* __restrict__ Bw,
                                                       u16* __restrict__ qb,
                                                       u16* __restrict__ kb,
                                                       u16* __restrict__ vb) {
  __shared__ alignas(16) u16 As[128 * 32];
  __shared__ alignas(16) u16 Bs[128 * 32];
  const int K = 1024;
  int f = blockIdx.x;
  int xcd = f & 7, idx = f >> 3;          // 8 XCDs x 96 blocks
  int nt = xcd * 3 + idx % 3;             // 0..23
  int mt = idx / 3;                       // 0..31
  int tid = threadIdx.x, wave = tid >> 6, lane = tid & 63, quad = lane >> 4, l15 = lane & 15;
  int m0 = mt * 128, n0 = nt * 128;
  f32x4 z = {0.f, 0.f, 0.f, 0.f};
  f32x4 acc[4][4];
  for (int i = 0; i < 4; i++) for (int j = 0; j < 4; j++) acc[i][j] = z;
  int r0 = tid >> 2;
  int kos = ((tid & 3) ^ ((r0 >> 1) & 3)) * 8;  // pre-swizzled global chunk
  const u16* ga0 = A + (m0 + r0) * K + kos;
  const u16* ga1 = A + (m0 + r0 + 64) * K + kos;   // ((r0+64)>>1)&3 == (r0>>1)&3
  const u16* gb0 = Bw + (n0 + r0) * K + kos;
  const u16* gb1 = Bw + (n0 + r0 + 64) * K + kos;
  u16 *la0 = &As[tid * 8], *la1 = &As[(256 + tid) * 8];   // linear dests
  u16 *lb0 = &Bs[tid * 8], *lb1 = &Bs[(256 + tid) * 8];
  int ar = (wave & 1) * 64, bc = (wave >> 1) * 64;
  int cA = (quad ^ ((l15 >> 1) & 3)) * 8;  // swizzled read chunk
  for (int k0 = 0; k0 < K; k0 += 32) {
    gld16(ga0 + k0, la0); gld16(ga1 + k0, la1);
    gld16(gb0 + k0, lb0); gld16(gb1 + k0, lb1);
    __syncthreads();
    bf16x8 af[4], bfr[4];
    for (int i = 0; i < 4; i++) af[i]  = *(const bf16x8*)&As[(ar + i * 16 + l15) * 32 + cA];
    for (int j = 0; j < 4; j++) bfr[j] = *(const bf16x8*)&Bs[(bc + j * 16 + l15) * 32 + cA];
    for (int i = 0; i < 4; i++)
      for (int j = 0; j < 4; j++)
        acc[i][j] = __builtin_amdgcn_mfma_f32_16x16x32_bf16(af[i], bfr[j], acc[i][j], 0, 0, 0);
    __syncthreads();
  }
  int which = n0 >> 10;  // block-uniform: 0=q 1=k 2=v
  u16* dst = which == 0 ? qb : (which == 1 ? kb : vb);
  float qs = which == 0 ? 0.045112882054311f : 1.0f;  // (1/32)*log2(e)
  for (int i = 0; i < 4; i++)
    for (int j = 0; j < 4; j++) {
      int o = n0 + bc + j * 16 + l15;
      int h = (o & 1023) >> 6, d = o & 63;
      for (int r = 0; r < 4; r++) {
        int m = m0 + ar + i * 16 + quad * 4 + r;
        int b = m >> 11, l = m & 2047;
        dst[((b * 16 + h) * 2048 + l) * 64 + d] = f2bf(acc[i][j][r] * qs);
      }
    }
}

// v[bh][l][d] -> vt[bh][d][l'], where within each 32-key tile the stored key
// order is the kappa slot order: stored position p holds key
// k = ((p>>3)&3)*4 + (p&3) + 16*((p>>2)&1)   (p = quad*8 + w).
// This makes flash's PV B-fragment a single b128 per d-block.
__global__ __launch_bounds__(256) void transpose_v_kernel(const u16* __restrict__ vb,
                                                          u16* __restrict__ vtb) {
  __shared__ alignas(16) u16 T[64 * 72];
  int lt = blockIdx.x, bh = blockIdx.y;
  int t = threadIdx.x;
  for (int ld = 0; ld < 2; ld++) {
    int idx = ld * 256 + t;
    int l = idx >> 3, d0 = (idx & 7) * 8;
    uint4 v = *(const uint4*)(vb + (bh * 2048 + lt * 64 + l) * 64 + d0);
    *(uint4*)&T[l * 72 + d0] = v;
  }
  __syncthreads();
  for (int ld = 0; ld < 2; ld++) {
    int idx = ld * 256 + t;
    int d = idx >> 3, p0 = (idx & 7) * 8;
    int sub = p0 >> 5, quad = (p0 >> 3) & 3;
    union { u16 us[8]; uint4 v; } tmp;
    for (int w2 = 0; w2 < 8; w2++) {
      int k = sub * 32 + quad * 4 + (w2 & 3) + 16 * (w2 >> 2);
      tmp.us[w2] = T[k * 72 + d];
    }
    *(uint4*)(vtb + (bh * 64 + d) * 2048 + lt * 64 + p0) = tmp.v;
  }
}

// Flash attention v10 (r13 verified, 44.9us): 128 threads = 2 waves x 32
// q-rows, 64-row q-tile, 32-key tiles x 32 iterations, keys split in half.
// Grid: flat 2048 blocks, bijective XCD remap (each XCD owns 4 bh; K/V
// L2-resident, FETCH 12.3MB verified). K/V: LDS dbuf DMA, XOR-swizzled.
// Swapped QK: s = mfma(K,Q) = S^T, lane l15 = q; exp2 + v_cvt_pk_bf16_f32
// pack in register forms the PV A-fragment under kappa; V pre-permuted to
// kappa order so the B-fragment is one conflict-free b128 per d-block.
// Denominator from unrounded exp values. LDS 16384 B.
__global__ __launch_bounds__(128, 4) void flash_kernel(const u16* __restrict__ qb,
                                                       const u16* __restrict__ kb,
                                                       const u16* __restrict__ vtb,
                                                       u16* __restrict__ pO0,
                                                       u16* __restrict__ pO1,
                                                       float* __restrict__ dn) {
  __shared__ alignas(16) u16 Ks[2][32 * 64];
  __shared__ alignas(16) u16 Vts[2][64 * 32];
  int f = blockIdx.x;
  int w = (f & 7) * 256 + (f >> 3);  // bijective XCD grouping (T1)
  int bh = w >> 6, ph = (w >> 5) & 1, qt = w & 31;
  int b = bh >> 4, h = bh & 15;
  int tid = threadIdx.x, wave = tid >> 6, lane = tid & 63, quad = lane >> 4, l15 = lane & 15;
  int q0 = qt * 64;
  int kbase = ph * 1024;  // this block's key range: kbase .. kbase+1023
  u16* pO = ph ? pO1 : pO0;
  const u16* qg = qb + (bh * 2048 + q0) * 64;
  const u16* kgb = kb + (bh * 2048 + kbase) * 64;
  const u16* vgb = vtb + bh * 64 * 2048 + kbase;

  // Q fragments: direct global->VGPR, once (16B contiguous rows of qb;
  // vmcnt retires before the kt loop — not barrier-drained per iteration)
  bf16x8 aq[2][2];
  for (int i = 0; i < 2; i++)
    for (int kk = 0; kk < 2; kk++)
      aq[i][kk] = *(const bf16x8*)(qg + (wave * 32 + i * 16 + l15) * 64 + kk * 32 + quad * 8);

  // stage K/V tile 0 into buffer 0 (4 KB each; 128 thr x 2 iters x 16 B)
  for (int it = 0; it < 2; it++) {
    int idx = it * 128 + tid;
    int kr = idx >> 3, kblk = (idx & 7) ^ (kr & 7);
    gld16(kgb + kr * 64 + kblk * 8, &Ks[0][idx * 8]);
    int vr = idx >> 2, vblk = (idx & 3) ^ ((vr >> 1) & 3);
    gld16(vgb + vr * 2048 + vblk * 8, &Vts[0][idx * 8]);
  }
  __syncthreads();

  f32x4 z = {0.f, 0.f, 0.f, 0.f};
  f32x4 o_[2][4];
  for (int i = 0; i < 2; i++) for (int j = 0; j < 4; j++) o_[i][j] = z;
  float dnacc[2] = {0.f, 0.f};

  // K fragment addresses (XOR swizzle, verified r8): row l15, logical k-chunk
  // quad (kbA) / quad+4 (kbB); physical = logical ^ (l15&7).
  int kro = l15 * 64;
  int kbA = 8 * ((quad) ^ (l15 & 7));
  int kbB = 8 * ((4 + quad) ^ (l15 & 7));
  // V b128 read offset (kappa-ordered vtb): row l15 (stride 32 u16), logical
  // 8-slot block quad, physical = quad ^ ((l15>>1)&3)  (r11 pattern, 0 conf).
  int vro = l15 * 32 + 8 * (quad ^ ((l15 >> 1) & 3));

#pragma unroll 2
  for (int kt = 0; kt < 32; kt++) {
    int cur = kt & 1;
    if (kt < 31) {  // DMA-prefetch next K/V tile into alternate buffer
      int nxt = cur ^ 1;
      for (int it = 0; it < 2; it++) {
        int idx = it * 128 + tid;
        int kr = idx >> 3, kblk = (idx & 7) ^ (kr & 7);
        gld16(kgb + ((kt + 1) * 32 + kr) * 64 + kblk * 8, &Ks[nxt][idx * 8]);
        int vr = idx >> 2, vblk = (idx & 3) ^ ((vr >> 1) & 3);
        gld16(vgb + vr * 2048 + (kt + 1) * 32 + vblk * 8, &Vts[nxt][idx * 8]);
      }
    }
    const u16* ks = Ks[cur];
    const u16* vs = Vts[cur];
    // K fragments: 4 b128 (j = key block 0/1, kk = k half)
    bf16x8 bk[2][2];
    for (int j = 0; j < 2; j++) {
      bk[j][0] = *(const bf16x8*)&ks[j * 1024 + kro + kbA];
      bk[j][1] = *(const bf16x8*)&ks[j * 1024 + kro + kbB];
    }
    // Swapped QK: S^T[key][q] (lane: col=l15=q, row=quad*4+r=key), K=64
    f32x4 s[2][2];
    __builtin_amdgcn_s_setprio(1);
    for (int i = 0; i < 2; i++)
      for (int j = 0; j < 2; j++) {
        s[i][j] = __builtin_amdgcn_mfma_f32_16x16x32_bf16(bk[j][0], aq[i][0], z, 0, 0, 0);
        s[i][j] = __builtin_amdgcn_mfma_f32_16x16x32_bf16(bk[j][1], aq[i][1], s[i][j], 0, 0, 0);
      }
    __builtin_amdgcn_s_setprio(0);
    // exp2 (Q pre-scaled) -> PV A-fragment via v_cvt_pk_bf16_f32 (RNE; slot w
    // holds key kappa(quad,w)). Denominator accumulates unrounded exp values.
    bf16x8 ap[2];
    for (int i = 0; i < 2; i++) {
      unsigned w4[4];
      for (int j = 0; j < 2; j++)
        for (int rp = 0; rp < 2; rp++) {
          float pa = __builtin_amdgcn_exp2f(s[i][j][2 * rp]);
          float pb = __builtin_amdgcn_exp2f(s[i][j][2 * rp + 1]);
          asm("v_cvt_pk_bf16_f32 %0, %1, %2" : "=v"(w4[j * 2 + rp]) : "v"(pa), "v"(pb));
          dnacc[i] += pa + pb;
        }
      union { uint4 u; bf16x8 v; } apu;
      apu.u.x = w4[0]; apu.u.y = w4[1]; apu.u.z = w4[2]; apu.u.w = w4[3];
      ap[i] = apu.v;
    }
    // V fragments: 4 b128 (j = d block), kappa slot order, conflict-free
    bf16x8 bv[4];
    for (int j = 0; j < 4; j++) bv[j] = *(const bf16x8*)&vs[j * 512 + vro];
    // PV: O[q][d] += P kappa-slots x V kappa-slots (K=32, 1 MFMA per (i,j))
    __builtin_amdgcn_s_setprio(1);
    for (int i = 0; i < 2; i++)
      for (int j = 0; j < 4; j++)
        o_[i][j] = __builtin_amdgcn_mfma_f32_16x16x32_bf16(ap[i], bv[j], o_[i][j], 0, 0, 0);
    __builtin_amdgcn_s_setprio(0);
    __syncthreads();  // drains next-tile DMA (only DMA is in flight); fences reuse
  }
  // denominator: lane (l15=q) holds partial sum over its quad's keys;
  // reduce across quads (lanes l15+16*quad), then quad 0 writes.
  for (int i = 0; i < 2; i++) {
    dnacc[i] += __shfl_xor(dnacc[i], 16, 64);
    dnacc[i] += __shfl_xor(dnacc[i], 32, 64);
  }
  // partial numerator (bf16) + partial denominator (fp32)
  for (int i = 0; i < 2; i++) {
    for (int j = 0; j < 4; j++) {
      int c = h * 64 + j * 16 + l15;
      for (int r = 0; r < 4; r++) {
        int q = q0 + wave * 32 + i * 16 + quad * 4 + r;
        pO[(b * 2048 + q) * 1024 + c] = f2bf(o_[i][j][r]);
      }
    }
    if (quad == 0) {
      int q = q0 + wave * 32 + i * 16 + l15;
      dn[ph * 65536 + bh * 2048 + q] = dnacc[i];
    }
  }
}

// out[M,N] = combine(pO0,pO1,dn)[M,K] * B[N,K]^T + bias[N], fp32 out.
// 128x64 tile, flat 512 blocks. M-MAJOR bijective XCD grouping: XCD x owns
// mt [4x,4x+4) x all 16 nt -> per-XCD working set A (pO rows) 2MB + B (wout)
// 2MB, both L2-resident (r23's n-major layout thrashed: FETCH 68.6MB).
// A is produced IN-STAGE: A[m][c] = cvt_pk((pO0+pO1) * 1/(dn0+dn1)) —
// reg-stage at the pre-swizzled source column, ds_write_b128 to the linear
// LDS slot (read side unchanged). Bit-identical to the combine+DMA path.
__global__ __launch_bounds__(256) void gemm_out_kernel(const u16* __restrict__ pO0,
                                                       const u16* __restrict__ pO1,
                                                       const float* __restrict__ dnb,
                                                       const u16* __restrict__ Bw,
                                                       const float* __restrict__ bias,
                                                       float* __restrict__ out) {
  __shared__ alignas(16) u16 As[128 * 32];
  __shared__ alignas(16) u16 Bs[64 * 32];
  const int K = 1024;
  int f = blockIdx.x;
  int xcd = f & 7, idx = f >> 3;          // 8 XCDs x 64 blocks
  int mt = xcd * 4 + (idx & 3);           // 0..31 (m-major: XCD owns 4 mt)
  int nt = idx >> 2;                      // 0..15
  int tid = threadIdx.x, wave = tid >> 6, lane = tid & 63, quad = lane >> 4, l15 = lane & 15;
  int m0 = mt * 128, n0 = nt * 64;
  f32x4 z = {0.f, 0.f, 0.f, 0.f};
  f32x4 acc[4][2];
  for (int i = 0; i < 4; i++) for (int j = 0; j < 2; j++) acc[i][j] = z;
  int r0 = tid >> 2;
  int kos = ((tid & 3) ^ ((r0 >> 1) & 3)) * 8;  // pre-swizzled global chunk
  int mA0 = m0 + r0, mA1 = m0 + r0 + 64;
  const u16* p0a = pO0 + mA0 * 1024 + kos;
  const u16* p1a = pO1 + mA0 * 1024 + kos;
  const u16* p0b = pO0 + mA1 * 1024 + kos;
  const u16* p1b = pO1 + mA1 * 1024 + kos;
  // dn row bases: li(m,h) = ((m>>11)*16 + h)*2048 + (m&2047)
  const float* dna = dnb + (mA0 >> 11) * 32768 + (mA0 & 2047);
  const float* dnc = dnb + (mA1 >> 11) * 32768 + (mA1 & 2047);
  const u16* gb0 = Bw + (n0 + r0) * K + kos;
  u16 *la0 = &As[tid * 8], *la1 = &As[(256 + tid) * 8];   // linear dests
  u16 *lb0 = &Bs[tid * 8];
  int ar = (wave & 1) * 64, bc = (wave >> 1) * 32;
  int cA = (quad ^ ((l15 >> 1) & 3)) * 8;  // swizzled read chunk
  for (int k0 = 0; k0 < K; k0 += 32) {
    // B: async DMA (as before)
    gld16(gb0 + k0, lb0);
    // A: reg-stage + combine. h = (k0+kos)>>6 constant over the 8 elems.
    int ho = ((k0 + kos) >> 6) * 2048;
    float inv0 = 1.0f / (dna[ho] + dna[65536 + ho]);
    float inv1 = 1.0f / (dnc[ho] + dnc[65536 + ho]);
    uint4 u0 = *(const uint4*)(p0a + k0);
    uint4 u1 = *(const uint4*)(p1a + k0);
    uint4 u2 = *(const uint4*)(p0b + k0);
    uint4 u3 = *(const uint4*)(p1b + k0);
    uint4 w0, w1;
    {
      const unsigned* a = (const unsigned*)&u0;
      const unsigned* bq = (const unsigned*)&u1;
      unsigned* wp = (unsigned*)&w0;
      for (int i = 0; i < 4; i++) {
        float lo = (bf2f(a[i] & 0xffff) + bf2f(bq[i] & 0xffff)) * inv0;
        float hi = (bf2f(a[i] >> 16)    + bf2f(bq[i] >> 16))    * inv0;
        asm("v_cvt_pk_bf16_f32 %0, %1, %2" : "=v"(wp[i]) : "v"(lo), "v"(hi));
      }
      const unsigned* c = (const unsigned*)&u2;
      const unsigned* d = (const unsigned*)&u3;
      unsigned* wq = (unsigned*)&w1;
      for (int i = 0; i < 4; i++) {
        float lo = (bf2f(c[i] & 0xffff) + bf2f(d[i] & 0xffff)) * inv1;
        float hi = (bf2f(c[i] >> 16)    + bf2f(d[i] >> 16))    * inv1;
        asm("v_cvt_pk_bf16_f32 %0, %1, %2" : "=v"(wq[i]) : "v"(lo), "v"(hi));
      }
    }
    *(uint4*)la0 = w0;
    *(uint4*)la1 = w1;
    __syncthreads();
    bf16x8 af[4], bfr[2];
    for (int i = 0; i < 4; i++) af[i]  = *(const bf16x8*)&As[(ar + i * 16 + l15) * 32 + cA];
    for (int j = 0; j < 2; j++) bfr[j] = *(const bf16x8*)&Bs[(bc + j * 16 + l15) * 32 + cA];
    for (int i = 0; i < 4; i++)
      for (int j = 0; j < 2; j++)
        acc[i][j] = __builtin_amdgcn_mfma_f32_16x16x32_bf16(af[i], bfr[j], acc[i][j], 0, 0, 0);
    __syncthreads();
  }
  for (int i = 0; i < 4; i++)
    for (int j = 0; j < 2; j++) {
      int o = n0 + bc + j * 16 + l15;
      float bo = bias[o];
      for (int r = 0; r < 4; r++) {
        int m = m0 + ar + i * 16 + quad * 4 + r;
        out[m * 1024 + o] = acc[i][j][r] + bo;
      }
    }
}

extern "C" void kernel_launch(void* const* d_in, const int* in_sizes, int n_in,
                              void* d_out, int out_size, void* d_ws, size_t ws_size,
                              hipStream_t stream) {
  const float* x     = (const float*)d_in[0];
  const float* w_qkv = (const float*)d_in[1];
  const float* w_out = (const float*)d_in[2];
  const float* b_out = (const float*)d_in[3];
  float* out = (float*)d_out;
  u16* ws = (u16*)d_ws;
  u16* x_bf    = ws;             // 4194304  (dead after gemm_qkv -> reused as pO0)
  u16* wqkv_bf = ws + 4194304;   // 3145728  (dead after gemm_qkv -> reused as dn)
  u16* wout_bf = ws + 7340032;   // 1048576  (live until gemm_out)
  u16* qb      = ws + 8388608;   // 4194304  [B,H,L,64] (pre-scaled)
  u16* kb      = ws + 12582912;  // 4194304  [B,H,L,64]
  u16* vb      = ws + 16777216;  // 4194304  (dead after transpose_v -> reused as pO1)
  u16* vtb     = ws + 20971520;  // 4194304  [B,H,64,L] (kappa key order)
  u16* pO0     = x_bf;           // partial numerator, key half 0 (bf16)
  u16* pO1     = vb;             // partial numerator, key half 1 (bf16)
  float* dnb   = (float*)wqkv_bf; // partial denominators [2][32][2048] fp32

  cvt_all_kernel<<<8192, 256, 0, stream>>>(x, w_qkv, w_out, x_bf, wqkv_bf, wout_bf);
  gemm_qkv_kernel<<<768, 256, 0, stream>>>(x_bf, wqkv_bf, qb, kb, vb);
  transpose_v_kernel<<<dim3(32, 32), 256, 0, stream>>>(vb, vtb);
  flash_kernel<<<2048, 128, 0, stream>>>(qb, kb, vtb, pO0, pO1, dnb);
  gemm_out_kernel<<<512, 256, 0, stream>>>(pO0, pO1, dnb, wout_bf, b_out, out);
}

// Round 15
// 190.782 us; speedup vs baseline: 1.0853x; 1.0669x over previous
//
#include <hip/hip_runtime.h>

// Attention block: x[2,2048,1024] fp32, w_qkv[3072,1024], w_out[1024,1024], b_out[1024]
// bf16 MFMA GEMMs + flash attention.
// Round 25: r24's m-major fixed gemm_out's thrash (FETCH 68.6->16.7MB) but it
// stayed 45us: the fused A-stage chain [A-loads -> combine -> ds_write ->
// __syncthreads] is fully latency-exposed (syncthreads drains vmcnt(0); 2
// blocks/CU = no TLP). Fix: order-robust 1-iteration-ahead pipeline — B DMA
// into dbuf LDS + A into regs, both prefetched for ks+1 at iter ks; the wait
// vmcnt(5) only requires prior-iteration ops landed (count independent of
// intra-iteration issue order). dn moved to a one-time LDS inv-table
// (stride 17), removing per-iter scattered loads + count instability.
// Same rcp/cvt_pk math -> bit-identical output. Others byte-identical r24.

typedef __attribute__((ext_vector_type(4))) float f32x4;
typedef __attribute__((ext_vector_type(8))) __bf16 bf16x8;
typedef unsigned short u16;

#define DEV static __device__ __forceinline__

DEV u16 f2bf(float x) {  // RNE float->bf16 (epilogues only)
  union { float f; unsigned u; } c; c.f = x;
  unsigned r = c.u + 0x7FFFu + ((c.u >> 16) & 1u);
  return (u16)(r >> 16);
}

DEV float bf2f(unsigned lo16) {  // bf16 (in low 16 bits) -> float
  union { unsigned u; float f; } c; c.u = lo16 << 16; return c.f;
}

DEV void gld16(const void* g, void* l) {  // async global->LDS, 16B/lane
  __builtin_amdgcn_global_load_lds((__attribute__((address_space(1))) void*)g,
                                   (__attribute__((address_space(3))) void*)l, 16, 0, 0);
}

// Fused fp32->bf16 convert for all three tensors (one dispatch).
__global__ __launch_bounds__(256) void cvt_all_kernel(const float* __restrict__ x,
                                                      const float* __restrict__ wq,
                                                      const float* __restrict__ wo,
                                                      u16* __restrict__ xo,
                                                      u16* __restrict__ wqo,
                                                      u16* __restrict__ woo) {
  int t = blockIdx.x * 256 + threadIdx.x;
  const float* in; u16* out; int i;
  if (t < 1048576)       { in = x;  out = xo;  i = t; }
  else if (t < 1835008)  { in = wq; out = wqo; i = t - 1048576; }
  else                   { in = wo; out = woo; i = t - 1835008; }
  float4 v = ((const float4*)in)[i];
  uint2 o;
  o.x = (unsigned)f2bf(v.x) | ((unsigned)f2bf(v.y) << 16);
  o.y = (unsigned)f2bf(v.z) | ((unsigned)f2bf(v.w) << 16);
  ((uint2*)out)[i] = o;
}

// C = A[M,K] * B[N,K]^T, 128x128 tile, BK=32, 4 waves of 64x64, bf16 MFMA.
// Grid: flat 768 blocks, bijective XCD grouping. Source-side chunk-XOR
// swizzle (rule #21). Single-buffered (r21 verified; dbuf regressed r22).
// Epilogue: scatter to q/k/v buffers [B=2,H=16,L=2048,Dh=64] bf16.
// Q is pre-scaled by scale*log2(e) so flash can exp2 the raw MFMA output.
__global__ __launch_bounds__(256) void gemm_qkv_kernel(const u16* __restrict__ A,
                                                       const u16* __restrict__ Bw,
                                                       u16* __restrict__ qb,
                                                       u16* __restrict__ kb,
                                                       u16* __restrict__ vb) {
  __shared__ alignas(16) u16 As[128 * 32];
  __shared__ alignas(16) u16 Bs[128 * 32];
  const int K = 1024;
  int f = blockIdx.x;
  int xcd = f & 7, idx = f >> 3;          // 8 XCDs x 96 blocks
  int nt = xcd * 3 + idx % 3;             // 0..23
  int mt = idx / 3;                       // 0..31
  int tid = threadIdx.x, wave = tid >> 6, lane = tid & 63, quad = lane >> 4, l15 = lane & 15;
  int m0 = mt * 128, n0 = nt * 128;
  f32x4 z = {0.f, 0.f, 0.f, 0.f};
  f32x4 acc[4][4];
  for (int i = 0; i < 4; i++) for (int j = 0; j < 4; j++) acc[i][j] = z;
  int r0 = tid >> 2;
  int kos = ((tid & 3) ^ ((r0 >> 1) & 3)) * 8;  // pre-swizzled global chunk
  const u16* ga0 = A + (m0 + r0) * K + kos;
  const u16* ga1 = A + (m0 + r0 + 64) * K + kos;   // ((r0+64)>>1)&3 == (r0>>1)&3
  const u16* gb0 = Bw + (n0 + r0) * K + kos;
  const u16* gb1 = Bw + (n0 + r0 + 64) * K + kos;
  u16 *la0 = &As[tid * 8], *la1 = &As[(256 + tid) * 8];   // linear dests
  u16 *lb0 = &Bs[tid * 8], *lb1 = &Bs[(256 + tid) * 8];
  int ar = (wave & 1) * 64, bc = (wave >> 1) * 64;
  int cA = (quad ^ ((l15 >> 1) & 3)) * 8;  // swizzled read chunk
  for (int k0 = 0; k0 < K; k0 += 32) {
    gld16(ga0 + k0, la0); gld16(ga1 + k0, la1);
    gld16(gb0 + k0, lb0); gld16(gb1 + k0, lb1);
    __syncthreads();
    bf16x8 af[4], bfr[4];
    for (int i = 0; i < 4; i++) af[i]  = *(const bf16x8*)&As[(ar + i * 16 + l15) * 32 + cA];
    for (int j = 0; j < 4; j++) bfr[j] = *(const bf16x8*)&Bs[(bc + j * 16 + l15) * 32 + cA];
    for (int i = 0; i < 4; i++)
      for (int j = 0; j < 4; j++)
        acc[i][j] = __builtin_amdgcn_mfma_f32_16x16x32_bf16(af[i], bfr[j], acc[i][j], 0, 0, 0);
    __syncthreads();
  }
  int which = n0 >> 10;  // block-uniform: 0=q 1=k 2=v
  u16* dst = which == 0 ? qb : (which == 1 ? kb : vb);
  float qs = which == 0 ? 0.045112882054311f : 1.0f;  // (1/32)*log2(e)
  for (int i = 0; i < 4; i++)
    for (int j = 0; j < 4; j++) {
      int o = n0 + bc + j * 16 + l15;
      int h = (o & 1023) >> 6, d = o & 63;
      for (int r = 0; r < 4; r++) {
        int m = m0 + ar + i * 16 + quad * 4 + r;
        int b = m >> 11, l = m & 2047;
        dst[((b * 16 + h) * 2048 + l) * 64 + d] = f2bf(acc[i][j][r] * qs);
      }
    }
}

// v[bh][l][d] -> vt[bh][d][l'], where within each 32-key tile the stored key
// order is the kappa slot order: stored position p holds key
// k = ((p>>3)&3)*4 + (p&3) + 16*((p>>2)&1)   (p = quad*8 + w).
// This makes flash's PV B-fragment a single b128 per d-block.
__global__ __launch_bounds__(256) void transpose_v_kernel(const u16* __restrict__ vb,
                                                          u16* __restrict__ vtb) {
  __shared__ alignas(16) u16 T[64 * 72];
  int lt = blockIdx.x, bh = blockIdx.y;
  int t = threadIdx.x;
  for (int ld = 0; ld < 2; ld++) {
    int idx = ld * 256 + t;
    int l = idx >> 3, d0 = (idx & 7) * 8;
    uint4 v = *(const uint4*)(vb + (bh * 2048 + lt * 64 + l) * 64 + d0);
    *(uint4*)&T[l * 72 + d0] = v;
  }
  __syncthreads();
  for (int ld = 0; ld < 2; ld++) {
    int idx = ld * 256 + t;
    int d = idx >> 3, p0 = (idx & 7) * 8;
    int sub = p0 >> 5, quad = (p0 >> 3) & 3;
    union { u16 us[8]; uint4 v; } tmp;
    for (int w2 = 0; w2 < 8; w2++) {
      int k = sub * 32 + quad * 4 + (w2 & 3) + 16 * (w2 >> 2);
      tmp.us[w2] = T[k * 72 + d];
    }
    *(uint4*)(vtb + (bh * 64 + d) * 2048 + lt * 64 + p0) = tmp.v;
  }
}

// Flash attention v10 (r13 verified, 44.9us): 128 threads = 2 waves x 32
// q-rows, 64-row q-tile, 32-key tiles x 32 iterations, keys split in half.
// Grid: flat 2048 blocks, bijective XCD remap (each XCD owns 4 bh; K/V
// L2-resident, FETCH 12.3MB verified). K/V: LDS dbuf DMA, XOR-swizzled.
// Swapped QK: s = mfma(K,Q) = S^T, lane l15 = q; exp2 + v_cvt_pk_bf16_f32
// pack in register forms the PV A-fragment under kappa; V pre-permuted to
// kappa order so the B-fragment is one conflict-free b128 per d-block.
// Denominator from unrounded exp values. LDS 16384 B.
__global__ __launch_bounds__(128, 4) void flash_kernel(const u16* __restrict__ qb,
                                                       const u16* __restrict__ kb,
                                                       const u16* __restrict__ vtb,
                                                       u16* __restrict__ pO0,
                                                       u16* __restrict__ pO1,
                                                       float* __restrict__ dn) {
  __shared__ alignas(16) u16 Ks[2][32 * 64];
  __shared__ alignas(16) u16 Vts[2][64 * 32];
  int f = blockIdx.x;
  int w = (f & 7) * 256 + (f >> 3);  // bijective XCD grouping (T1)
  int bh = w >> 6, ph = (w >> 5) & 1, qt = w & 31;
  int b = bh >> 4, h = bh & 15;
  int tid = threadIdx.x, wave = tid >> 6, lane = tid & 63, quad = lane >> 4, l15 = lane & 15;
  int q0 = qt * 64;
  int kbase = ph * 1024;  // this block's key range: kbase .. kbase+1023
  u16* pO = ph ? pO1 : pO0;
  const u16* qg = qb + (bh * 2048 + q0) * 64;
  const u16* kgb = kb + (bh * 2048 + kbase) * 64;
  const u16* vgb = vtb + bh * 64 * 2048 + kbase;

  // Q fragments: direct global->VGPR, once (16B contiguous rows of qb;
  // vmcnt retires before the kt loop — not barrier-drained per iteration)
  bf16x8 aq[2][2];
  for (int i = 0; i < 2; i++)
    for (int kk = 0; kk < 2; kk++)
      aq[i][kk] = *(const bf16x8*)(qg + (wave * 32 + i * 16 + l15) * 64 + kk * 32 + quad * 8);

  // stage K/V tile 0 into buffer 0 (4 KB each; 128 thr x 2 iters x 16 B)
  for (int it = 0; it < 2; it++) {
    int idx = it * 128 + tid;
    int kr = idx >> 3, kblk = (idx & 7) ^ (kr & 7);
    gld16(kgb + kr * 64 + kblk * 8, &Ks[0][idx * 8]);
    int vr = idx >> 2, vblk = (idx & 3) ^ ((vr >> 1) & 3);
    gld16(vgb + vr * 2048 + vblk * 8, &Vts[0][idx * 8]);
  }
  __syncthreads();

  f32x4 z = {0.f, 0.f, 0.f, 0.f};
  f32x4 o_[2][4];
  for (int i = 0; i < 2; i++) for (int j = 0; j < 4; j++) o_[i][j] = z;
  float dnacc[2] = {0.f, 0.f};

  // K fragment addresses (XOR swizzle, verified r8): row l15, logical k-chunk
  // quad (kbA) / quad+4 (kbB); physical = logical ^ (l15&7).
  int kro = l15 * 64;
  int kbA = 8 * ((quad) ^ (l15 & 7));
  int kbB = 8 * ((4 + quad) ^ (l15 & 7));
  // V b128 read offset (kappa-ordered vtb): row l15 (stride 32 u16), logical
  // 8-slot block quad, physical = quad ^ ((l15>>1)&3)  (r11 pattern, 0 conf).
  int vro = l15 * 32 + 8 * (quad ^ ((l15 >> 1) & 3));

#pragma unroll 2
  for (int kt = 0; kt < 32; kt++) {
    int cur = kt & 1;
    if (kt < 31) {  // DMA-prefetch next K/V tile into alternate buffer
      int nxt = cur ^ 1;
      for (int it = 0; it < 2; it++) {
        int idx = it * 128 + tid;
        int kr = idx >> 3, kblk = (idx & 7) ^ (kr & 7);
        gld16(kgb + ((kt + 1) * 32 + kr) * 64 + kblk * 8, &Ks[nxt][idx * 8]);
        int vr = idx >> 2, vblk = (idx & 3) ^ ((vr >> 1) & 3);
        gld16(vgb + vr * 2048 + (kt + 1) * 32 + vblk * 8, &Vts[nxt][idx * 8]);
      }
    }
    const u16* ks = Ks[cur];
    const u16* vs = Vts[cur];
    // K fragments: 4 b128 (j = key block 0/1, kk = k half)
    bf16x8 bk[2][2];
    for (int j = 0; j < 2; j++) {
      bk[j][0] = *(const bf16x8*)&ks[j * 1024 + kro + kbA];
      bk[j][1] = *(const bf16x8*)&ks[j * 1024 + kro + kbB];
    }
    // Swapped QK: S^T[key][q] (lane: col=l15=q, row=quad*4+r=key), K=64
    f32x4 s[2][2];
    __builtin_amdgcn_s_setprio(1);
    for (int i = 0; i < 2; i++)
      for (int j = 0; j < 2; j++) {
        s[i][j] = __builtin_amdgcn_mfma_f32_16x16x32_bf16(bk[j][0], aq[i][0], z, 0, 0, 0);
        s[i][j] = __builtin_amdgcn_mfma_f32_16x16x32_bf16(bk[j][1], aq[i][1], s[i][j], 0, 0, 0);
      }
    __builtin_amdgcn_s_setprio(0);
    // exp2 (Q pre-scaled) -> PV A-fragment via v_cvt_pk_bf16_f32 (RNE; slot w
    // holds key kappa(quad,w)). Denominator accumulates unrounded exp values.
    bf16x8 ap[2];
    for (int i = 0; i < 2; i++) {
      unsigned w4[4];
      for (int j = 0; j < 2; j++)
        for (int rp = 0; rp < 2; rp++) {
          float pa = __builtin_amdgcn_exp2f(s[i][j][2 * rp]);
          float pb = __builtin_amdgcn_exp2f(s[i][j][2 * rp + 1]);
          asm("v_cvt_pk_bf16_f32 %0, %1, %2" : "=v"(w4[j * 2 + rp]) : "v"(pa), "v"(pb));
          dnacc[i] += pa + pb;
        }
      union { uint4 u; bf16x8 v; } apu;
      apu.u.x = w4[0]; apu.u.y = w4[1]; apu.u.z = w4[2]; apu.u.w = w4[3];
      ap[i] = apu.v;
    }
    // V fragments: 4 b128 (j = d block), kappa slot order, conflict-free
    bf16x8 bv[4];
    for (int j = 0; j < 4; j++) bv[j] = *(const bf16x8*)&vs[j * 512 + vro];
    // PV: O[q][d] += P kappa-slots x V kappa-slots (K=32, 1 MFMA per (i,j))
    __builtin_amdgcn_s_setprio(1);
    for (int i = 0; i < 2; i++)
      for (int j = 0; j < 4; j++)
        o_[i][j] = __builtin_amdgcn_mfma_f32_16x16x32_bf16(ap[i], bv[j], o_[i][j], 0, 0, 0);
    __builtin_amdgcn_s_setprio(0);
    __syncthreads();  // drains next-tile DMA (only DMA is in flight); fences reuse
  }
  // denominator: lane (l15=q) holds partial sum over its quad's keys;
  // reduce across quads (lanes l15+16*quad), then quad 0 writes.
  for (int i = 0; i < 2; i++) {
    dnacc[i] += __shfl_xor(dnacc[i], 16, 64);
    dnacc[i] += __shfl_xor(dnacc[i], 32, 64);
  }
  // partial numerator (bf16) + partial denominator (fp32)
  for (int i = 0; i < 2; i++) {
    for (int j = 0; j < 4; j++) {
      int c = h * 64 + j * 16 + l15;
      for (int r = 0; r < 4; r++) {
        int q = q0 + wave * 32 + i * 16 + quad * 4 + r;
        pO[(b * 2048 + q) * 1024 + c] = f2bf(o_[i][j][r]);
      }
    }
    if (quad == 0) {
      int q = q0 + wave * 32 + i * 16 + l15;
      dn[ph * 65536 + bh * 2048 + q] = dnacc[i];
    }
  }
}

// out[M,N] = combine(pO0,pO1,dn)[M,K] * B[N,K]^T + bias[N], fp32 out.
// 128x64 tile, flat 512 blocks, M-MAJOR XCD grouping (per-XCD A 2MB + B 2MB
// L2-resident, FETCH=compulsory verified r24). Pipelined fused A-stage:
// B (LDS dbuf DMA) and A (regs) prefetched ONE ITERATION AHEAD; the wait
// vmcnt(5) (= this iter's 1 DMA + 4 A-loads) only requires prior-iteration
// ops landed — robust to intra-iteration issue order. dn -> one-time LDS
// inv-table (stride 17, bank-spread); h = ks>>1 (kos-independent).
__global__ __launch_bounds__(256) void gemm_out_kernel(const u16* __restrict__ pO0,
                                                       const u16* __restrict__ pO1,
                                                       const float* __restrict__ dnb,
                                                       const u16* __restrict__ Bw,
                                                       const float* __restrict__ bias,
                                                       float* __restrict__ out) {
  __shared__ alignas(16) u16 As[128 * 32];
  __shared__ alignas(16) u16 Bs[2][64 * 32];
  __shared__ float Itab[128 * 17];
  const int K = 1024;
  int f = blockIdx.x;
  int xcd = f & 7, idx = f >> 3;          // 8 XCDs x 64 blocks
  int mt = xcd * 4 + (idx & 3);           // 0..31 (m-major: XCD owns 4 mt)
  int nt = idx >> 2;                      // 0..15
  int tid = threadIdx.x, wave = tid >> 6, lane = tid & 63, quad = lane >> 4, l15 = lane & 15;
  int m0 = mt * 128, n0 = nt * 64;
  f32x4 z = {0.f, 0.f, 0.f, 0.f};
  f32x4 acc[4][2];
  for (int i = 0; i < 4; i++) for (int j = 0; j < 2; j++) acc[i][j] = z;
  int r0 = tid >> 2;
  int kos = ((tid & 3) ^ ((r0 >> 1) & 3)) * 8;  // pre-swizzled global chunk
  int mA0 = m0 + r0, mA1 = m0 + r0 + 64;
  const u16* p0a = pO0 + mA0 * 1024 + kos;
  const u16* p1a = pO1 + mA0 * 1024 + kos;
  const u16* p0b = pO0 + mA1 * 1024 + kos;
  const u16* p1b = pO1 + mA1 * 1024 + kos;
  const u16* gb0 = Bw + (n0 + r0) * K + kos;
  u16 *la0 = &As[tid * 8], *la1 = &As[(256 + tid) * 8];   // linear dests
  int ar = (wave & 1) * 64, bc = (wave >> 1) * 32;
  int cA = (quad ^ ((l15 >> 1) & 3)) * 8;  // swizzled read chunk

  // one-time inv table: Itab[row][h] = 1/(dn0+dn1) for rows m0..m0+127
  for (int i = 0; i < 8; i++) {
    int e = i * 256 + tid;                // 2048 entries
    int row = e & 127, h = e >> 7;
    int m = m0 + row;
    int li = ((m >> 11) * 16 + h) * 2048 + (m & 2047);
    Itab[row * 17 + h] = 1.0f / (dnb[li] + dnb[65536 + li]);
  }
  __syncthreads();

  // prologue: B(0) DMA + A(0) regs
  gld16(gb0, &Bs[0][tid * 8]);
  uint4 a0 = *(const uint4*)p0a;
  uint4 a1 = *(const uint4*)p1a;
  uint4 a2 = *(const uint4*)p0b;
  uint4 a3 = *(const uint4*)p1b;

  for (int ks = 0; ks < 32; ks++) {
    int cur = ks & 1;
    uint4 n0v, n1v, n2v, n3v;
    if (ks < 31) {  // prefetch ks+1: B DMA into alt buffer + A into regs
      int k1 = (ks + 1) * 32;
      gld16(gb0 + k1, &Bs[cur ^ 1][tid * 8]);
      n0v = *(const uint4*)(p0a + k1);
      n1v = *(const uint4*)(p1a + k1);
      n2v = *(const uint4*)(p0b + k1);
      n3v = *(const uint4*)(p1b + k1);
    }
    // combine current A regs (landed: issued last iteration)
    float inv0 = Itab[r0 * 17 + (ks >> 1)];
    float inv1 = Itab[(r0 + 64) * 17 + (ks >> 1)];
    uint4 w0, w1;
    {
      const unsigned* a = (const unsigned*)&a0;
      const unsigned* bq = (const unsigned*)&a1;
      unsigned* wp = (unsigned*)&w0;
      for (int i = 0; i < 4; i++) {
        float lo = (bf2f(a[i] & 0xffff) + bf2f(bq[i] & 0xffff)) * inv0;
        float hi = (bf2f(a[i] >> 16)    + bf2f(bq[i] >> 16))    * inv0;
        asm("v_cvt_pk_bf16_f32 %0, %1, %2" : "=v"(wp[i]) : "v"(lo), "v"(hi));
      }
      const unsigned* c = (const unsigned*)&a2;
      const unsigned* d = (const unsigned*)&a3;
      unsigned* wq = (unsigned*)&w1;
      for (int i = 0; i < 4; i++) {
        float lo = (bf2f(c[i] & 0xffff) + bf2f(d[i] & 0xffff)) * inv1;
        float hi = (bf2f(c[i] >> 16)    + bf2f(d[i] >> 16))    * inv1;
        asm("v_cvt_pk_bf16_f32 %0, %1, %2" : "=v"(wq[i]) : "v"(lo), "v"(hi));
      }
    }
    *(uint4*)la0 = w0;
    *(uint4*)la1 = w1;
    // wait: B(ks) DMA + A(ks) (prev-iter) landed; this iter's 5 stay in flight
    if (ks < 31) asm volatile("s_waitcnt vmcnt(5) lgkmcnt(0)" ::: "memory");
    else         asm volatile("s_waitcnt vmcnt(0) lgkmcnt(0)" ::: "memory");
    __builtin_amdgcn_s_barrier();
    const u16* bs = Bs[cur];
    bf16x8 af[4], bfr[2];
    for (int i = 0; i < 4; i++) af[i]  = *(const bf16x8*)&As[(ar + i * 16 + l15) * 32 + cA];
    for (int j = 0; j < 2; j++) bfr[j] = *(const bf16x8*)&bs[(bc + j * 16 + l15) * 32 + cA];
    for (int i = 0; i < 4; i++)
      for (int j = 0; j < 2; j++)
        acc[i][j] = __builtin_amdgcn_mfma_f32_16x16x32_bf16(af[i], bfr[j], acc[i][j], 0, 0, 0);
    asm volatile("s_waitcnt lgkmcnt(0)" ::: "memory");
    __builtin_amdgcn_s_barrier();
    if (ks < 31) { a0 = n0v; a1 = n1v; a2 = n2v; a3 = n3v; }
  }
  for (int i = 0; i < 4; i++)
    for (int j = 0; j < 2; j++) {
      int o = n0 + bc + j * 16 + l15;
      float bo = bias[o];
      for (int r = 0; r < 4; r++) {
        int m = m0 + ar + i * 16 + quad * 4 + r;
        out[m * 1024 + o] = acc[i][j][r] + bo;
      }
    }
}

extern "C" void kernel_launch(void* const* d_in, const int* in_sizes, int n_in,
                              void* d_out, int out_size, void* d_ws, size_t ws_size,
                              hipStream_t stream) {
  const float* x     = (const float*)d_in[0];
  const float* w_qkv = (const float*)d_in[1];
  const float* w_out = (const float*)d_in[2];
  const float* b_out = (const float*)d_in[3];
  float* out = (float*)d_out;
  u16* ws = (u16*)d_ws;
  u16* x_bf    = ws;             // 4194304  (dead after gemm_qkv -> reused as pO0)
  u16* wqkv_bf = ws + 4194304;   // 3145728  (dead after gemm_qkv -> reused as dn)
  u16* wout_bf = ws + 7340032;   // 1048576  (live until gemm_out)
  u16* qb      = ws + 8388608;   // 4194304  [B,H,L,64] (pre-scaled)
  u16* kb      = ws + 12582912;  // 4194304  [B,H,L,64]
  u16* vb      = ws + 16777216;  // 4194304  (dead after transpose_v -> reused as pO1)
  u16* vtb     = ws + 20971520;  // 4194304  [B,H,64,L] (kappa key order)
  u16* pO0     = x_bf;           // partial numerator, key half 0 (bf16)
  u16* pO1     = vb;             // partial numerator, key half 1 (bf16)
  float* dnb   = (float*)wqkv_bf; // partial denominators [2][32][2048] fp32

  cvt_all_kernel<<<8192, 256, 0, stream>>>(x, w_qkv, w_out, x_bf, wqkv_bf, wout_bf);
  gemm_qkv_kernel<<<768, 256, 0, stream>>>(x_bf, wqkv_bf, qb, kb, vb);
  transpose_v_kernel<<<dim3(32, 32), 256, 0, stream>>>(vb, vtb);
  flash_kernel<<<2048, 128, 0, stream>>>(qb, kb, vtb, pO0, pO1, dnb);
  gemm_out_kernel<<<512, 256, 0, stream>>>(pO0, pO1, dnb, wout_bf, b_out, out);
}